// Round 10
// baseline (218.296 us; speedup 1.0000x reference)
//
#include <hip/hip_runtime.h>
#include <float.h>

#define NTOK   2048
#define VOCAB  32000
#define DIM    512
#define NCHUNK 50
#define NT16   2000               // 16-col vocab tiles
#define TPC    40                 // tiles per chunk
#define NSUP   5                  // supersteps per chunk (8 tiles each)
#define ROWSB  64                 // rows per block (4 waves x 16 rows)
#define NRB    (NTOK / ROWSB)     // 32
#define TILE_BYTES 8192           // 16 cols x 512 k x 1B fp8, fragment-linear

typedef __attribute__((ext_vector_type(4))) float f32x4;
typedef unsigned int u32;
typedef long long i64;

template<int N> struct IC { static constexpr int v = N; };

// pack 8 consecutive fp32 (k..k+7) into 8 fp8-e4m3 bytes (k-order = byte order)
__device__ __forceinline__ i64 pack_fp8x8(f32x4 x0, f32x4 x1) {
    int lo = __builtin_amdgcn_cvt_pk_fp8_f32(x0.x, x0.y, 0, false);
    lo = __builtin_amdgcn_cvt_pk_fp8_f32(x0.z, x0.w, lo, true);
    int hi = __builtin_amdgcn_cvt_pk_fp8_f32(x1.x, x1.y, 0, false);
    hi = __builtin_amdgcn_cvt_pk_fp8_f32(x1.z, x1.w, hi, true);
    return (i64)(((unsigned long long)(u32)hi << 32) | (u32)lo);
}

__device__ __forceinline__ void async_copy16(void* lds, const void* g) {
    __builtin_amdgcn_global_load_lds(
        (const __attribute__((address_space(1))) u32*)(const u32*)g,
        (__attribute__((address_space(3))) u32*)(u32*)lds, 16, 0, 0);
}

__global__ void init_out(float* out) {
    if (threadIdx.x < 2) out[threadIdx.x] = 0.f;
}

// ---- precast: emb fp32 -> fp8 FRAGMENT-LINEAR 16-col-tile image + e2 ----
// i64 at tile*8192 + ks*512 + il*8 holds emb[v0+(il&15)][ks*32+(il>>4)*8+j].
__global__ __launch_bounds__(256) void precast_kernel(
    const float* __restrict__ emb, char* __restrict__ Bbf, float* __restrict__ e2) {
    const int tile = blockIdx.x;
    const int t = threadIdx.x, w = t >> 6, l = t & 63;
    const int v0 = tile * 16;
    char* tbase = Bbf + (size_t)tile * TILE_BYTES;
    #pragma unroll
    for (int it = 0; it < 4; ++it) {
        const int v = it * 4 + w;
        const float* src = emb + (size_t)(v0 + v) * DIM + l * 8;
        f32x4 x0 = *(const f32x4*)src;
        f32x4 x1 = *(const f32x4*)(src + 4);
        float sq = x0.x*x0.x + x0.y*x0.y + x0.z*x0.z + x0.w*x0.w
                 + x1.x*x1.x + x1.y*x1.y + x1.z*x1.z + x1.w*x1.w;
        #pragma unroll
        for (int m = 1; m < 64; m <<= 1) sq += __shfl_xor(sq, m);
        if (l == 0) e2[v0 + v] = sq;
        *(i64*)(tbase + (l >> 2) * 512 + ((l & 3) * 16 + v) * 8) = pack_fp8x8(x0, x1);
    }
}

// e2-only fallback
__global__ __launch_bounds__(256) void e2_kernel(const float* __restrict__ emb,
                                                 float* __restrict__ e2) {
    int gid = blockIdx.x * 256 + threadIdx.x;
    int wid = gid >> 6, l = gid & 63;
    if (wid >= VOCAB) return;
    const float* row = emb + (size_t)wid * DIM + l * 8;
    f32x4 a = *(const f32x4*)row;
    f32x4 b = *(const f32x4*)(row + 4);
    float s = a.x*a.x + a.y*a.y + a.z*a.z + a.w*a.w
            + b.x*b.x + b.y*b.y + b.z*b.z + b.w*b.w;
    #pragma unroll
    for (int m = 1; m < 64; m <<= 1) s += __shfl_xor(s, m);
    if (l == 0) e2[wid] = s;
}

// ---- fused: fp8 MFMA; q in 512B/row superstep bursts -> LDS -> regs;
// B 3-ahead via 5 rotating LDS buffers with hardcoded counted vmcnt ----
template<bool PRECAST>
__global__ __launch_bounds__(256, 2) void fused_kernel(
    const float* __restrict__ pred_ll, const int* __restrict__ target,
    const float* __restrict__ emb, const char* __restrict__ Bbf,
    const float* __restrict__ e2g,
    float* __restrict__ partials /* [NTOK][NCHUNK][2] */) {

    const int rb = blockIdx.x;
    const int ch = blockIdx.y;
    const int t  = threadIdx.x;
    const int w  = t >> 6;                // 0..3
    const int l  = t & 63;
    const int l15 = l & 15;
    const int lg  = l >> 4;               // 0..3

    __shared__ __align__(16) char  ldsB[5][TILE_BYTES];  // 40 KB fp8 B tiles
    __shared__ __align__(16) float ldsQ[64 * 128];       // 32 KB q superstep
    __shared__ __align__(16) float e2l[1024];            // 4 KB (640 used)

    const int t0 = ch * TPC;
    const int rowblk = rb * ROWSB;
    const int rowbase = rowblk + w * 16;

    // A fragments: 16 gold rows per wave, fp8, 32 regs
    i64 afrag[16];
    {
        const int grow = target[rowbase + l15];
        if constexpr (PRECAST) {
            const char* ab = Bbf + (size_t)(grow >> 4) * TILE_BYTES
                           + ((l & 48) + (grow & 15)) * 8;
            #pragma unroll
            for (int ks = 0; ks < 16; ++ks)
                afrag[ks] = *(const i64*)(ab + ks * 512);
        } else {
            const float* gsrc = emb + (size_t)grow * DIM;
            #pragma unroll
            for (int ks = 0; ks < 16; ++ks) {
                const int k0 = ks * 32 + ((l >> 4) << 3);
                afrag[ks] = pack_fp8x8(*(const f32x4*)(gsrc + k0),
                                       *(const f32x4*)(gsrc + k0 + 4));
            }
        }
    }
    float g2[4];
    #pragma unroll
    for (int r = 0; r < 4; ++r) g2[r] = e2g[target[rowbase + lg * 4 + r]];

    float s_[4] = {0.f, 0.f, 0.f, 0.f};
    float ac_[4] = {0.f, 0.f, 0.f, 0.f};

    if constexpr (!PRECAST) {
        // correctness fallback: simple per-tile sync, VALU staging, direct q
        for (int g = t0; g < t0 + TPC; ++g) {
            __syncthreads();
            #pragma unroll
            for (int it = 0; it < 4; ++it) {
                const int slot = it * 256 + t, ks = slot >> 6, il = slot & 63;
                const int v = il & 15, k0 = ks * 32 + ((il >> 4) << 3);
                const float* src = emb + (size_t)(g * 16 + v) * DIM + k0;
                *(i64*)(ldsB[0] + ks * 512 + il * 8) =
                    pack_fp8x8(*(const f32x4*)src, *(const f32x4*)(src + 4));
            }
            __syncthreads();
            f32x4 acc = {0.f, 0.f, 0.f, 0.f};
            #pragma unroll
            for (int ks = 0; ks < 16; ++ks) {
                const i64 bb = *(const i64*)(ldsB[0] + ks * 512 + l * 8);
                acc = __builtin_amdgcn_mfma_f32_16x16x32_fp8_fp8(afrag[ks], bb, acc, 0, 0, 0);
            }
            const float e2v = e2g[g * 16 + l15];
            #pragma unroll
            for (int r = 0; r < 4; ++r) {
                const float q = pred_ll[(size_t)(rowbase + lg * 4 + r) * VOCAB + g * 16 + l15];
                float d2 = fmaxf(fmaf(-2.f, acc[r], g2[r] + e2v), 1e-12f);
                const float e = __expf(-sqrtf(d2));
                s_[r] += e;
                ac_[r] = fmaf(e, -q, ac_[r]);
            }
        }
    } else {
        float qreg[4][8];

        auto stageQ = [&](int k) {   // 8 gll/thread, 512B/row bursts
            const int colf = (t0 + k * 8) * 16;
            #pragma unroll
            for (int j = 0; j < 8; ++j) {
                const int f = j * 256 + t;
                async_copy16((char*)ldsQ + (size_t)(j * 4096 + t * 16),
                             pred_ll + (size_t)(rowblk + (f >> 5)) * VOCAB
                                     + colf + (f & 31) * 4);
            }
        };
        auto stageB = [&](int g) {   // 2 gll/thread
            char* dst = ldsB[(g - t0) % 5];
            const char* src = Bbf + (size_t)g * TILE_BYTES;
            async_copy16(dst + t * 16, src + t * 16);
            async_copy16(dst + 4096 + t * 16, src + 4096 + t * 16);
        };

        // flush prelude reg-loads so the counted region starts clean
        asm volatile("s_waitcnt vmcnt(0)" ::: "memory");

        // prologue: e2 (1 gll, clamped uniform) + Q(0) (8) + B(t0..t0+3) (8)
        {
            int src = ch * (TPC * 16) + t * 4;
            if (src > VOCAB - 4) src = VOCAB - 4;
            async_copy16(e2l + t * 4, e2g + src);
        }
        stageQ(0);
        stageB(t0); stageB(t0 + 1); stageB(t0 + 2); stageB(t0 + 3);

        auto step = [&](int b, auto Iw, auto Xw, auto Dw) {
            constexpr int i = decltype(Iw)::v;
            constexpr int X = decltype(Xw)::v;
            constexpr bool D = decltype(Dw)::v != 0;
            const int g = b + i;
            // wait THIS wave's B(g) slice retired, then barrier -> all slices in
            asm volatile("s_waitcnt vmcnt(%0)" :: "i"(X) : "memory");
            __builtin_amdgcn_s_barrier();
            __builtin_amdgcn_sched_barrier(0);
            if constexpr (D) stageB(g + 4);
            const char* lb = ldsB[(g - t0) % 5];
            f32x4 acc = {0.f, 0.f, 0.f, 0.f};
            #pragma unroll
            for (int ks = 0; ks < 16; ++ks) {
                const i64 bb = *(const i64*)(lb + ks * 512 + l * 8);
                acc = __builtin_amdgcn_mfma_f32_16x16x32_fp8_fp8(afrag[ks], bb, acc, 0, 0, 0);
            }
            const float e2v = e2l[(g - t0) * 16 + l15];
            #pragma unroll
            for (int r = 0; r < 4; ++r) {
                float d2 = fmaxf(fmaf(-2.f, acc[r], g2[r] + e2v), 1e-12f);
                const float e = __expf(-sqrtf(d2));
                s_[r] += e;
                ac_[r] = fmaf(e, -qreg[r][i], ac_[r]);
            }
        };

        auto boundary = [&](int k) {
            // sup0: retires e2+Q(0), leaves B(t0..t0+3); later sups: no-op
            asm volatile("s_waitcnt vmcnt(8)" ::: "memory");
            #pragma unroll
            for (int r = 0; r < 4; ++r)
                #pragma unroll
                for (int i = 0; i < 8; ++i)
                    qreg[r][i] = ldsQ[(w * 16 + lg * 4 + r) * 128 + i * 16 + l15];
            asm volatile("s_waitcnt lgkmcnt(0)" ::: "memory");
            __builtin_amdgcn_s_barrier();   // q LDS free for overwrite
            if (k + 1 < NSUP) stageQ(k + 1);
        };

        #pragma unroll 1
        for (int k = 0; k < NSUP - 1; ++k) {
            const int b = t0 + k * 8;
            boundary(k);
            step(b, IC<0>{}, IC<14>{}, IC<1>{});
            step(b, IC<1>{}, IC<14>{}, IC<1>{});
            step(b, IC<2>{}, IC<14>{}, IC<1>{});
            step(b, IC<3>{}, IC<14>{}, IC<1>{});
            step(b, IC<4>{}, IC<6>{},  IC<1>{});   // forces Q(k+1): 4-tile cover
            step(b, IC<5>{}, IC<6>{},  IC<1>{});
            step(b, IC<6>{}, IC<6>{},  IC<1>{});
            step(b, IC<7>{}, IC<6>{},  IC<1>{});
        }
        {   // last superstep: no Q stage, B stages end at t0+39
            const int b = t0 + (NSUP - 1) * 8;
            boundary(NSUP - 1);
            step(b, IC<0>{}, IC<6>{}, IC<1>{});
            step(b, IC<1>{}, IC<6>{}, IC<1>{});
            step(b, IC<2>{}, IC<6>{}, IC<1>{});
            step(b, IC<3>{}, IC<6>{}, IC<1>{});
            step(b, IC<4>{}, IC<6>{}, IC<0>{});
            step(b, IC<5>{}, IC<4>{}, IC<0>{});
            step(b, IC<6>{}, IC<2>{}, IC<0>{});
            step(b, IC<7>{}, IC<0>{}, IC<0>{});
        }
    }

    // combine 16 col-slices within each 16-lane group
    #pragma unroll
    for (int r = 0; r < 4; ++r) {
        float sv = s_[r], av = ac_[r];
        #pragma unroll
        for (int m = 1; m < 16; m <<= 1) {
            sv += __shfl_xor(sv, m);
            av += __shfl_xor(av, m);
        }
        if (l15 == 0) {
            const int rg = rowbase + lg * 4 + r;
            float* pp = partials + ((size_t)rg * NCHUNK + ch) * 2;
            pp[0] = sv; pp[1] = av;
        }
    }
}

__global__ __launch_bounds__(256) void reduce_kernel(
    const float* __restrict__ pred_ll, const int* __restrict__ target,
    const float* __restrict__ partials, float* __restrict__ out) {
    const int row = blockIdx.x * 256 + threadIdx.x;
    float loss = 0.f, nll = 0.f;
    if (row < NTOK) {
        const int tg = target[row];
        const float mask = (tg != 0) ? 1.f : 0.f;
        const float* pp = partials + (size_t)row * NCHUNK * 2;
        float S = 0.f, A = 0.f;
        #pragma unroll 5
        for (int c = 0; c < NCHUNK; ++c) { S += pp[c * 2]; A += pp[c * 2 + 1]; }
        loss = mask * (A / S);
        nll  = mask * (-pred_ll[(size_t)row * VOCAB + tg]);
    }
    #pragma unroll
    for (int o = 32; o > 0; o >>= 1) {
        loss += __shfl_xor(loss, o);
        nll  += __shfl_xor(nll, o);
    }
    if ((threadIdx.x & 63) == 0) {
        atomicAdd(&out[0], loss);
        atomicAdd(&out[1], nll);
    }
}

extern "C" void kernel_launch(void* const* d_in, const int* in_sizes, int n_in,
                              void* d_out, int out_size, void* d_ws, size_t ws_size,
                              hipStream_t stream) {
    const float* pred_ll = (const float*)d_in[0];
    const int*   target  = (const int*)d_in[1];
    const float* emb     = (const float*)d_in[2];
    float* out = (float*)d_out;

    // ws layout: [e2: VOCAB f32][partials: NTOK*NCHUNK*2 f32][fp8 image 16MB]
    float* e2       = (float*)d_ws;
    float* partials = e2 + VOCAB;
    const size_t base = (size_t)VOCAB * 4 + (size_t)NTOK * NCHUNK * 2 * 4;
    char* Bbf       = (char*)d_ws + base;
    const size_t need = base + (size_t)NT16 * TILE_BYTES;
    const bool precast = (ws_size >= need);

    hipLaunchKernelGGL(init_out, dim3(1), dim3(64), 0, stream, out);
    if (precast) {
        hipLaunchKernelGGL(precast_kernel, dim3(NT16), dim3(256), 0, stream, emb, Bbf, e2);
        hipLaunchKernelGGL((fused_kernel<true>), dim3(NRB, NCHUNK), dim3(256), 0, stream,
                           pred_ll, target, emb, Bbf, e2, partials);
    } else {
        hipLaunchKernelGGL(e2_kernel, dim3(VOCAB * 64 / 256), dim3(256), 0, stream, emb, e2);
        hipLaunchKernelGGL((fused_kernel<false>), dim3(NRB, NCHUNK), dim3(256), 0, stream,
                           pred_ll, target, emb, Bbf, e2, partials);
    }
    hipLaunchKernelGGL(reduce_kernel, dim3(NTOK / 256), dim3(256), 0, stream,
                       pred_ll, target, partials, out);
}